// Round 8
// baseline (194.475 us; speedup 1.0000x reference)
//
#include <hip/hip_runtime.h>
#include <hip/hip_bf16.h>
#include <stdint.h>

#define Bn 4
#define Cn 64
#define Fn 50000
#define Kn 16
#define NTOT (Bn*Fn)
#define EPS 1e-5f

typedef unsigned short u16;
typedef unsigned int u32;
typedef __attribute__((ext_vector_type(8))) short short8;
typedef __attribute__((ext_vector_type(4))) float f32x4;

__device__ __forceinline__ u16 f2bf(float x) {
  __hip_bfloat16 h = __float2bfloat16(x);
  return *reinterpret_cast<u16*>(&h);
}
__device__ __forceinline__ u32 pack2(float a, float b) {
  return (u32)f2bf(a) | ((u32)f2bf(b) << 16);
}
// async global->LDS, 16 B/lane; LDS dest = wave-uniform base + lane*16
__device__ __forceinline__ void gload_lds16(const float* g, float* l) {
  __builtin_amdgcn_global_load_lds(
      (const __attribute__((address_space(1))) u32*)(g),
      (__attribute__((address_space(3))) u32*)(l), 16, 0, 0);
}

// K1 (MFMA): Gt[(b*4+seg)][face][16ch] bf16 (32 B rows) = W x fea[b].
// Unchanged from round 7 (best measured). global_load_lds width=16 staging,
// pre-swizzled source, direct 512B-coalesced uint2 epilogue, folded memset.
__global__ __launch_bounds__(256) void k1_mfma(
    const float* __restrict__ fea, const float* __restrict__ W,
    u32* __restrict__ Gt, float* __restrict__ gsum) {
  const int b = blockIdx.y;
  const int f0 = blockIdx.x * 128;
  const int t = threadIdx.x;
  const int l = t & 63;
  const int quad = l >> 4;
  const int lane15 = l & 15;
  const int wv = t >> 6;
  __shared__ float a_s[64 * 128];   // 32 KB linear -> 5 blocks/CU

  if (blockIdx.x == 0 && b == 0 && t < 128) gsum[t] = 0.f;

  // Stage first (async DMA overlaps the A-frag build below).
  {
    const float* fb = fea + (size_t)b * Cn * Fn;
    #pragma unroll
    for (int i = 0; i < 8; i++) {
      const int ch = wv * 16 + 2 * i + (l >> 5);
      const int fblk = (l & 31) ^ ((((ch >> 3) & 3)) << 1);  // pre-swizzled src
      int fg = f0 + fblk * 4;
      if (fg >= Fn) fg = f0;        // clamp: garbage faces never consumed
      gload_lds16(fb + (size_t)ch * Fn + fg, &a_s[(wv * 16 + 2 * i) * 128]);
    }
  }

  // A-frags: o = ot*16 + lane15, c = kk*32 + quad*8 + j  (W 64x64, cache-hot)
  short8 afr[4][2];
  #pragma unroll
  for (int ot = 0; ot < 4; ot++) {
    #pragma unroll
    for (int kk = 0; kk < 2; kk++) {
      const float* wr = W + (ot * 16 + lane15) * 64 + kk * 32 + quad * 8;
      float4 wa = *(const float4*)wr;
      float4 wb = *(const float4*)(wr + 4);
      union { short8 v; u32 u[4]; } fr;
      fr.u[0] = pack2(wa.x, wa.y); fr.u[1] = pack2(wa.z, wa.w);
      fr.u[2] = pack2(wb.x, wb.y); fr.u[3] = pack2(wb.z, wb.w);
      afr[ot][kk] = fr.v;
    }
  }
  __syncthreads();   // drains the global_load_lds queue before first ds_read

  f32x4 acc[4][2];
  #pragma unroll
  for (int ot = 0; ot < 4; ot++)
    #pragma unroll
    for (int ft = 0; ft < 2; ft++) acc[ot][ft] = (f32x4){0.f, 0.f, 0.f, 0.f};

  #pragma unroll
  for (int ft = 0; ft < 2; ft++) {
    const int fl = wv * 32 + ft * 16 + lane15;
    const int fsw = fl ^ (quad << 3);       // read-side swizzle: ch-octet = quad
    float x[16];
    #pragma unroll
    for (int j = 0; j < 8; j++) x[j] = a_s[(quad * 8 + j) * 128 + fsw];
    #pragma unroll
    for (int j = 0; j < 8; j++) x[8 + j] = a_s[(32 + quad * 8 + j) * 128 + fsw];
    union { short8 s; u32 u[4]; } b0, b1;
    #pragma unroll
    for (int p = 0; p < 4; p++) {
      b0.u[p] = pack2(x[2 * p], x[2 * p + 1]);
      b1.u[p] = pack2(x[8 + 2 * p], x[8 + 2 * p + 1]);
    }
    #pragma unroll
    for (int ot = 0; ot < 4; ot++) {
      acc[ot][ft] = __builtin_amdgcn_mfma_f32_16x16x32_bf16(afr[ot][0], b0.s, acc[ot][ft], 0, 0, 0);
      acc[ot][ft] = __builtin_amdgcn_mfma_f32_16x16x32_bf16(afr[ot][1], b1.s, acc[ot][ft], 0, 0, 0);
    }
  }

  // Epilogue: seg = ot; per (ot,ft) instr 64 lanes = 512 B contiguous.
  #pragma unroll
  for (int ot = 0; ot < 4; ot++) {
    #pragma unroll
    for (int ft = 0; ft < 2; ft++) {
      int fg = f0 + wv * 32 + ft * 16 + lane15;
      if (fg < Fn) {
        uint2 pv;
        pv.x = pack2(acc[ot][ft][0], acc[ot][ft][1]);
        pv.y = pack2(acc[ot][ft][2], acc[ot][ft][3]);
        *(uint2*)(Gt + ((size_t)(b * 4 + ot) * Fn + fg) * 8 + quad * 2) = pv;
      }
    }
  }
}

// K2: seg-major gather, PERSISTENT (2048 blocks, 3-4 tiles each, balanced
// contiguous ranges). combo = bid&15 -> all blocks of a combo land on XCD
// combo%8 (1.6MB x2 per XCD L2). Stats in registers across tiles; one LDS
// transpose + atomic round per block. Ring indices prefetched across tiles.
template<int WRITE_BF16>
__global__ __launch_bounds__(256) void k2_gather(
    const u32* __restrict__ Gt, const int* __restrict__ ring,
    const float* __restrict__ bias, u32* __restrict__ Y, float* __restrict__ outF,
    float* __restrict__ gsum, float* __restrict__ gsum2) {
  const int bid = blockIdx.x;
  const int combo = bid & 15;
  const int sub = bid >> 4;           // 0..127
  const int b = combo >> 2;
  const int seg = combo & 3;
  const int t = threadIdx.x;
  const int face_l = t >> 1;          // 0..127
  const int half = t & 1;

  __shared__ float y_s[128][17];
  __shared__ float rs[16][17];
  __shared__ float rs2[16][17];

  const int c0 = seg * 16 + half * 8;
  float bv[8];
  #pragma unroll
  for (int i = 0; i < 8; i++) bv[i] = bias[c0 + i];

  const int NT = (Fn + 127) / 128;    // 391
  const int t_begin = sub * NT / 128;
  const int t_end = (sub + 1) * NT / 128;

  float sacc[8], s2acc[8];
  #pragma unroll
  for (int i = 0; i < 8; i++) { sacc[i] = 0.f; s2acc[i] = 0.f; }

  const uint4* Gs = (const uint4*)(Gt + (size_t)combo * Fn * 8);
  const int* rbase = ring + (size_t)b * Fn * Kn;

  // prefetch first tile's ring indices
  int4 r0, r1, r2, r3;
  {
    int fa = t_begin * 128 + face_l;
    int fc = fa < Fn ? fa : 0;
    const int4* rp = (const int4*)(rbase + (size_t)fc * Kn);
    r0 = rp[0]; r1 = rp[1]; r2 = rp[2]; r3 = rp[3];
  }

  for (int tile = t_begin; tile < t_end; ++tile) {
    const int fa = tile * 128 + face_l;
    const bool valid = fa < Fn;
    int idx[16] = {r0.x,r0.y,r0.z,r0.w, r1.x,r1.y,r1.z,r1.w,
                   r2.x,r2.y,r2.z,r2.w, r3.x,r3.y,r3.z,r3.w};

    if (tile + 1 < t_end) {           // prefetch next tile's indices
      int nfa = (tile + 1) * 128 + face_l;
      int nfc = nfa < Fn ? nfa : 0;
      const int4* rp = (const int4*)(rbase + (size_t)nfc * Kn);
      r0 = rp[0]; r1 = rp[1]; r2 = rp[2]; r3 = rp[3];
    }

    float acc[8];
    #pragma unroll
    for (int i = 0; i < 8; i++) acc[i] = 0.f;

    if (valid) {
      uint4 v[8], w[8];
      #pragma unroll
      for (int k = 0; k < 8; k++) v[k] = Gs[(size_t)idx[k] * 2 + half];
      #pragma unroll
      for (int k = 0; k < 8; k++) w[k] = Gs[(size_t)idx[8 + k] * 2 + half];
      #pragma unroll
      for (int k = 0; k < 8; k++) {
        u32 uu[4] = {v[k].x, v[k].y, v[k].z, v[k].w};
        #pragma unroll
        for (int p = 0; p < 4; p++) {
          acc[2*p]   += __uint_as_float(uu[p] << 16);
          acc[2*p+1] += __uint_as_float(uu[p] & 0xffff0000u);
        }
      }
      #pragma unroll
      for (int k = 0; k < 8; k++) {
        u32 uu[4] = {w[k].x, w[k].y, w[k].z, w[k].w};
        #pragma unroll
        for (int p = 0; p < 4; p++) {
          acc[2*p]   += __uint_as_float(uu[p] << 16);
          acc[2*p+1] += __uint_as_float(uu[p] & 0xffff0000u);
        }
      }
    }
    #pragma unroll
    for (int i = 0; i < 8; i++) acc[i] = valid ? acc[i] + bv[i] : 0.f;
    #pragma unroll
    for (int i = 0; i < 8; i++) {     // stats in registers (invalid adds 0)
      sacc[i] += acc[i];
      s2acc[i] += acc[i] * acc[i];
    }
    #pragma unroll
    for (int i = 0; i < 8; i++) y_s[face_l][half * 8 + i] = acc[i];
    __syncthreads();

    if (WRITE_BF16) {
      const int fp = t & 63, chb = t >> 6;   // 64 face-pairs x 4 ch-groups
      const int fa2 = tile * 64 + fp;
      if (fa2 * 2 < Fn) {
        #pragma unroll
        for (int j = 0; j < 4; j++) {
          int ch = chb * 4 + j;
          Y[((size_t)b * 64 + seg * 16 + ch) * (Fn / 2) + fa2] =
              pack2(y_s[fp * 2][ch], y_s[fp * 2 + 1][ch]);
        }
      }
    } else {
      const int fl2 = t & 127, chb = t >> 7;
      if (tile * 128 + fl2 < Fn) {
        float* ob = outF + ((size_t)b * 64 + seg * 16 + chb * 8) * Fn + tile * 128 + fl2;
        #pragma unroll
        for (int j = 0; j < 8; j++) ob[(size_t)j * Fn] = y_s[fl2][chb * 8 + j];
      }
    }
    __syncthreads();                  // y_s reuse guard
  }

  // block-level stats: transpose sacc/s2acc through y_s, two passes
  const int ch = t & 15, part = t >> 4;
  #pragma unroll
  for (int i = 0; i < 8; i++) y_s[face_l][half * 8 + i] = sacc[i];
  __syncthreads();
  {
    float s = 0.f;
    #pragma unroll
    for (int i = 0; i < 8; i++) s += y_s[part * 8 + i][ch];
    rs[part][ch] = s;
  }
  __syncthreads();
  #pragma unroll
  for (int i = 0; i < 8; i++) y_s[face_l][half * 8 + i] = s2acc[i];
  __syncthreads();
  {
    float s2 = 0.f;
    #pragma unroll
    for (int i = 0; i < 8; i++) s2 += y_s[part * 8 + i][ch];
    rs2[part][ch] = s2;
  }
  __syncthreads();
  if (t < 16) {
    float s = 0.f;
    #pragma unroll
    for (int p = 0; p < 16; p++) s += rs[p][t];
    atomicAdd(&gsum[seg * 16 + t], s);
  } else if (t < 32) {
    const int ch2 = t - 16;
    float s2 = 0.f;
    #pragma unroll
    for (int p = 0; p < 16; p++) s2 += rs2[p][ch2];
    atomicAdd(&gsum2[seg * 16 + ch2], s2);
  }
}

__global__ void k3_stats(const float* __restrict__ gsum, const float* __restrict__ gsum2,
                         const float* __restrict__ gamma, const float* __restrict__ beta,
                         float* __restrict__ ab) {
  int o = threadIdx.x;
  if (o < 64) {
    float inv = 1.0f / (float)NTOT;
    float mean = gsum[o] * inv;
    float var = gsum2[o] * inv - mean * mean;  // biased
    float r = rsqrtf(var + EPS);
    float a = gamma[o] * r;
    ab[o] = a;
    ab[64 + o] = beta[o] - mean * a;
  }
}

// k4 (bf16, k3 fused): thread = one uint2 (4 faces) -> one float4 store.
__global__ __launch_bounds__(256) void k4_norm_bf(
    const u32* __restrict__ Y, const float* __restrict__ gsum,
    const float* __restrict__ gsum2, const float* __restrict__ gamma,
    const float* __restrict__ beta, float* __restrict__ out) {
  int i = blockIdx.x * 256 + threadIdx.x;   // uint2 index; 3.2M total, exact cover
  int ch = (i / 12500) & 63;                // Fn/4 = 12500 uint2 per channel row
  const float inv = 1.0f / (float)NTOT;
  float mean = gsum[ch] * inv;
  float var = gsum2[ch] * inv - mean * mean;
  float a = gamma[ch] * rsqrtf(var + EPS);
  float cc = beta[ch] - mean * a;
  uint2 u = ((const uint2*)Y)[i];
  float4 v;
  v.x = fmaxf(fmaf(__uint_as_float(u.x << 16), a, cc), 0.f);
  v.y = fmaxf(fmaf(__uint_as_float(u.x & 0xffff0000u), a, cc), 0.f);
  v.z = fmaxf(fmaf(__uint_as_float(u.y << 16), a, cc), 0.f);
  v.w = fmaxf(fmaf(__uint_as_float(u.y & 0xffff0000u), a, cc), 0.f);
  ((float4*)out)[i] = v;
}

// k4 (fallback): in-place fp32 normalize
__global__ __launch_bounds__(256) void k4_norm_f32(float* __restrict__ out,
                                                   const float* __restrict__ ab) {
  int i = blockIdx.x * 256 + threadIdx.x;   // float4 index
  int o = (i / (Fn / 4)) & 63;
  float a = ab[o], c = ab[64 + o];
  float4 v = ((float4*)out)[i];
  v.x = fmaxf(fmaf(v.x, a, c), 0.f);
  v.y = fmaxf(fmaf(v.y, a, c), 0.f);
  v.z = fmaxf(fmaf(v.z, a, c), 0.f);
  v.w = fmaxf(fmaf(v.w, a, c), 0.f);
  ((float4*)out)[i] = v;
}

extern "C" void kernel_launch(void* const* d_in, const int* in_sizes, int n_in,
                              void* d_out, int out_size, void* d_ws, size_t ws_size,
                              hipStream_t stream) {
  const float* fea   = (const float*)d_in[0];
  const int*   ring  = (const int*)d_in[1];
  const float* W     = (const float*)d_in[2];
  const float* bias  = (const float*)d_in[3];
  const float* gamma = (const float*)d_in[4];
  const float* beta  = (const float*)d_in[5];
  float* out = (float*)d_out;

  u32* Gt = (u32*)d_ws;                                   // [B*4][Fn][8 u32] = 25.6 MB
  const size_t gtBytes = (size_t)Bn * 4 * Fn * 8 * 4;
  const size_t yBytes  = (size_t)Bn * 64 * (Fn / 2) * 4;  // 25.6 MB
  const bool bf16y = ws_size >= gtBytes + yBytes + 1024;

  u32* Y = (u32*)((char*)d_ws + gtBytes);
  float* gsum  = bf16y ? (float*)((char*)d_ws + gtBytes + yBytes)
                       : (float*)((char*)d_ws + gtBytes);
  float* gsum2 = gsum + 64;
  float* ab    = gsum + 128;

  // k1 zeroes gsum[0..127] -> no memset dispatch
  k1_mfma<<<dim3((Fn + 127) / 128, Bn), 256, 0, stream>>>(fea, W, Gt, gsum);
  if (bf16y) {
    k2_gather<1><<<dim3(2048), 256, 0, stream>>>(Gt, ring, bias, Y, out, gsum, gsum2);
    k4_norm_bf<<<dim3(Bn * 64 * 12500 / 256), 256, 0, stream>>>(Y, gsum, gsum2, gamma, beta, out);
  } else {
    k2_gather<0><<<dim3(2048), 256, 0, stream>>>(Gt, ring, bias, Y, out, gsum, gsum2);
    k3_stats<<<1, 64, 0, stream>>>(gsum, gsum2, gamma, beta, ab);
    k4_norm_f32<<<dim3((Bn * Cn * Fn / 4) / 256), 256, 0, stream>>>(out, ab);
  }
}

// Round 9
// 191.154 us; speedup vs baseline: 1.0174x; 1.0174x over previous
//
#include <hip/hip_runtime.h>
#include <hip/hip_bf16.h>
#include <stdint.h>

#define Bn 4
#define Cn 64
#define Fn 50000
#define Kn 16
#define NTOT (Bn*Fn)
#define EPS 1e-5f

typedef unsigned short u16;
typedef unsigned int u32;
typedef __attribute__((ext_vector_type(8))) short short8;
typedef __attribute__((ext_vector_type(4))) float f32x4;

__device__ __forceinline__ u16 f2bf(float x) {
  __hip_bfloat16 h = __float2bfloat16(x);
  return *reinterpret_cast<u16*>(&h);
}
__device__ __forceinline__ u32 pack2(float a, float b) {
  return (u32)f2bf(a) | ((u32)f2bf(b) << 16);
}
// async global->LDS, 16 B/lane; LDS dest = wave-uniform base + lane*16
__device__ __forceinline__ void gload_lds16(const float* g, float* l) {
  __builtin_amdgcn_global_load_lds(
      (const __attribute__((address_space(1))) u32*)(g),
      (__attribute__((address_space(3))) u32*)(l), 16, 0, 0);
}

// K1 (MFMA): Gt[(b*4+seg)][face][16ch] bf16 (32 B rows) = W x fea[b].
// global_load_lds width=16 staging (async DMA, no VGPR round-trip) into
// linear LDS [64ch][128f] fp32; SOURCE face-block pre-swizzled by
// channel-octet so frag reads are <=2-way bank aliased = free (m136/m173).
// MFMA layouts (m89-verified). Epilogue: direct uint2 stores, 512 B/instr.
// Also zeroes gsum (block 0,0) -> no separate memset dispatch.
__global__ __launch_bounds__(256) void k1_mfma(
    const float* __restrict__ fea, const float* __restrict__ W,
    u32* __restrict__ Gt, float* __restrict__ gsum) {
  const int b = blockIdx.y;
  const int f0 = blockIdx.x * 128;
  const int t = threadIdx.x;
  const int l = t & 63;
  const int quad = l >> 4;
  const int lane15 = l & 15;
  const int wv = t >> 6;
  __shared__ float a_s[64 * 128];   // 32 KB linear -> 5 blocks/CU

  if (blockIdx.x == 0 && b == 0 && t < 128) gsum[t] = 0.f;

  // Stage first (async DMA overlaps the A-frag build below).
  // Wave w stages channels 16w..16w+15: 8 issues x (2 ch: lane<32 / lane>=32).
  {
    const float* fb = fea + (size_t)b * Cn * Fn;
    #pragma unroll
    for (int i = 0; i < 8; i++) {
      const int ch = wv * 16 + 2 * i + (l >> 5);
      const int fblk = (l & 31) ^ ((((ch >> 3) & 3)) << 1);  // pre-swizzled src
      int fg = f0 + fblk * 4;
      if (fg >= Fn) fg = f0;        // clamp: garbage faces never consumed
      gload_lds16(fb + (size_t)ch * Fn + fg, &a_s[(wv * 16 + 2 * i) * 128]);
    }
  }

  // A-frags: o = ot*16 + lane15, c = kk*32 + quad*8 + j  (W 64x64, cache-hot)
  short8 afr[4][2];
  #pragma unroll
  for (int ot = 0; ot < 4; ot++) {
    #pragma unroll
    for (int kk = 0; kk < 2; kk++) {
      const float* wr = W + (ot * 16 + lane15) * 64 + kk * 32 + quad * 8;
      float4 wa = *(const float4*)wr;
      float4 wb = *(const float4*)(wr + 4);
      union { short8 v; u32 u[4]; } fr;
      fr.u[0] = pack2(wa.x, wa.y); fr.u[1] = pack2(wa.z, wa.w);
      fr.u[2] = pack2(wb.x, wb.y); fr.u[3] = pack2(wb.z, wb.w);
      afr[ot][kk] = fr.v;
    }
  }
  __syncthreads();   // drains the global_load_lds queue before first ds_read

  f32x4 acc[4][2];
  #pragma unroll
  for (int ot = 0; ot < 4; ot++)
    #pragma unroll
    for (int ft = 0; ft < 2; ft++) acc[ot][ft] = (f32x4){0.f, 0.f, 0.f, 0.f};

  #pragma unroll
  for (int ft = 0; ft < 2; ft++) {
    const int fl = wv * 32 + ft * 16 + lane15;
    const int fsw = fl ^ (quad << 3);       // read-side swizzle: ch-octet = quad
    float x[16];
    #pragma unroll
    for (int j = 0; j < 8; j++) x[j] = a_s[(quad * 8 + j) * 128 + fsw];
    #pragma unroll
    for (int j = 0; j < 8; j++) x[8 + j] = a_s[(32 + quad * 8 + j) * 128 + fsw];
    union { short8 s; u32 u[4]; } b0, b1;
    #pragma unroll
    for (int p = 0; p < 4; p++) {
      b0.u[p] = pack2(x[2 * p], x[2 * p + 1]);
      b1.u[p] = pack2(x[8 + 2 * p], x[8 + 2 * p + 1]);
    }
    #pragma unroll
    for (int ot = 0; ot < 4; ot++) {
      acc[ot][ft] = __builtin_amdgcn_mfma_f32_16x16x32_bf16(afr[ot][0], b0.s, acc[ot][ft], 0, 0, 0);
      acc[ot][ft] = __builtin_amdgcn_mfma_f32_16x16x32_bf16(afr[ot][1], b1.s, acc[ot][ft], 0, 0, 0);
    }
  }

  // Epilogue: o = ot*16 + quad*4 + r -> seg = ot; uint2 at u32-offset quad*2.
  // Per (ot,ft) instruction: 64 lanes cover 16 faces x 32 B = 512 B contiguous.
  #pragma unroll
  for (int ot = 0; ot < 4; ot++) {
    #pragma unroll
    for (int ft = 0; ft < 2; ft++) {
      int fg = f0 + wv * 32 + ft * 16 + lane15;
      if (fg < Fn) {
        uint2 pv;
        pv.x = pack2(acc[ot][ft][0], acc[ot][ft][1]);
        pv.y = pack2(acc[ot][ft][2], acc[ot][ft][3]);
        *(uint2*)(Gt + ((size_t)(b * 4 + ot) * Fn + fg) * 8 + quad * 2) = pv;
      }
    }
  }
}

// K2: round-7 structure (best measured: 67.5 us; persistence regressed via
// VGPR 56->80 occupancy drop; NT hints regressed -14%). One tile per block:
// block = (b,seg) x 128 faces, 32 B rows, 2 lanes/row, 56 VGPR.
template<int WRITE_BF16>
__global__ __launch_bounds__(256) void k2_gather(
    const u32* __restrict__ Gt, const int* __restrict__ ring,
    const float* __restrict__ bias, u32* __restrict__ Y, float* __restrict__ outF,
    float* __restrict__ gsum, float* __restrict__ gsum2) {
  const int bid = blockIdx.x;
  const int combo = bid & 15;
  const int ft = bid >> 4;
  const int b = combo >> 2;
  const int seg = combo & 3;
  const int t = threadIdx.x;
  const int face_l = t >> 1;          // 0..127
  const int half = t & 1;
  const int fa = ft * 128 + face_l;
  const bool valid = fa < Fn;

  __shared__ float y_s[128][17];
  __shared__ float rs[16][17];
  __shared__ float rs2[16][17];

  float acc[8];
  #pragma unroll
  for (int i = 0; i < 8; i++) acc[i] = 0.f;

  const int c0 = seg * 16 + half * 8;
  float bv[8];
  #pragma unroll
  for (int i = 0; i < 8; i++) bv[i] = bias[c0 + i];

  if (valid) {
    const int4* rp = (const int4*)(ring + ((size_t)b * Fn + fa) * Kn);
    int4 i0 = rp[0], i1 = rp[1], i2 = rp[2], i3 = rp[3];
    int idx[16] = {i0.x,i0.y,i0.z,i0.w, i1.x,i1.y,i1.z,i1.w,
                   i2.x,i2.y,i2.z,i2.w, i3.x,i3.y,i3.z,i3.w};
    const uint4* Gs = (const uint4*)(Gt + (size_t)combo * Fn * 8);
    uint4 v[8], w[8];
    #pragma unroll
    for (int k = 0; k < 8; k++) v[k] = Gs[(size_t)idx[k] * 2 + half];
    #pragma unroll
    for (int k = 0; k < 8; k++) w[k] = Gs[(size_t)idx[8 + k] * 2 + half];
    #pragma unroll
    for (int k = 0; k < 8; k++) {
      u32 uu[4] = {v[k].x, v[k].y, v[k].z, v[k].w};
      #pragma unroll
      for (int p = 0; p < 4; p++) {
        acc[2*p]   += __uint_as_float(uu[p] << 16);
        acc[2*p+1] += __uint_as_float(uu[p] & 0xffff0000u);
      }
    }
    #pragma unroll
    for (int k = 0; k < 8; k++) {
      u32 uu[4] = {w[k].x, w[k].y, w[k].z, w[k].w};
      #pragma unroll
      for (int p = 0; p < 4; p++) {
        acc[2*p]   += __uint_as_float(uu[p] << 16);
        acc[2*p+1] += __uint_as_float(uu[p] & 0xffff0000u);
      }
    }
  }
  #pragma unroll
  for (int i = 0; i < 8; i++) acc[i] = valid ? acc[i] + bv[i] : 0.f;
  #pragma unroll
  for (int i = 0; i < 8; i++) y_s[face_l][half * 8 + i] = acc[i];
  __syncthreads();

  if (WRITE_BF16) {
    const int fp = t & 63, chb = t >> 6;   // 64 face-pairs x 4 ch-groups
    const int fa2 = ft * 64 + fp;
    if (fa2 * 2 < Fn) {
      #pragma unroll
      for (int j = 0; j < 4; j++) {
        int ch = chb * 4 + j;
        Y[((size_t)b * 64 + seg * 16 + ch) * (Fn / 2) + fa2] =
            pack2(y_s[fp * 2][ch], y_s[fp * 2 + 1][ch]);
      }
    }
  } else {
    const int fl2 = t & 127, chb = t >> 7;
    if (ft * 128 + fl2 < Fn) {
      float* ob = outF + ((size_t)b * 64 + seg * 16 + chb * 8) * Fn + ft * 128 + fl2;
      #pragma unroll
      for (int j = 0; j < 8; j++) ob[(size_t)j * Fn] = y_s[fl2][chb * 8 + j];
    }
  }

  {  // stats: 16 parts x 16 channels
    const int ch = t & 15, part = t >> 4;
    float s = 0.f, s2 = 0.f;
    #pragma unroll
    for (int i = 0; i < 8; i++) {
      float v = y_s[part * 8 + i][ch];
      s += v; s2 += v * v;
    }
    rs[part][ch] = s; rs2[part][ch] = s2;
  }
  __syncthreads();
  if (t < 16) {
    float s = 0.f;
    #pragma unroll
    for (int p = 0; p < 16; p++) s += rs[p][t];
    atomicAdd(&gsum[seg * 16 + t], s);
  } else if (t < 32) {
    const int ch = t - 16;
    float s2 = 0.f;
    #pragma unroll
    for (int p = 0; p < 16; p++) s2 += rs2[p][ch];
    atomicAdd(&gsum2[seg * 16 + ch], s2);
  }
}

__global__ void k3_stats(const float* __restrict__ gsum, const float* __restrict__ gsum2,
                         const float* __restrict__ gamma, const float* __restrict__ beta,
                         float* __restrict__ ab) {
  int o = threadIdx.x;
  if (o < 64) {
    float inv = 1.0f / (float)NTOT;
    float mean = gsum[o] * inv;
    float var = gsum2[o] * inv - mean * mean;  // biased
    float r = rsqrtf(var + EPS);
    float a = gamma[o] * r;
    ab[o] = a;
    ab[64 + o] = beta[o] - mean * a;
  }
}

// k4 (bf16, k3 fused): thread = one uint2 (4 faces) -> one float4 store.
// Reads 512 B / writes 1 KB contiguous per wave instr (fully coalesced).
__global__ __launch_bounds__(256) void k4_norm_bf(
    const u32* __restrict__ Y, const float* __restrict__ gsum,
    const float* __restrict__ gsum2, const float* __restrict__ gamma,
    const float* __restrict__ beta, float* __restrict__ out) {
  int i = blockIdx.x * 256 + threadIdx.x;   // uint2 index; 3.2M total, exact cover
  int ch = (i / 12500) & 63;                // Fn/4 = 12500 uint2 per channel row
  const float inv = 1.0f / (float)NTOT;
  float mean = gsum[ch] * inv;
  float var = gsum2[ch] * inv - mean * mean;
  float a = gamma[ch] * rsqrtf(var + EPS);
  float cc = beta[ch] - mean * a;
  uint2 u = ((const uint2*)Y)[i];
  float4 v;
  v.x = fmaxf(fmaf(__uint_as_float(u.x << 16), a, cc), 0.f);
  v.y = fmaxf(fmaf(__uint_as_float(u.x & 0xffff0000u), a, cc), 0.f);
  v.z = fmaxf(fmaf(__uint_as_float(u.y << 16), a, cc), 0.f);
  v.w = fmaxf(fmaf(__uint_as_float(u.y & 0xffff0000u), a, cc), 0.f);
  ((float4*)out)[i] = v;
}

// k4 (fallback): in-place fp32 normalize
__global__ __launch_bounds__(256) void k4_norm_f32(float* __restrict__ out,
                                                   const float* __restrict__ ab) {
  int i = blockIdx.x * 256 + threadIdx.x;   // float4 index
  int o = (i / (Fn / 4)) & 63;
  float a = ab[o], c = ab[64 + o];
  float4 v = ((float4*)out)[i];
  v.x = fmaxf(fmaf(v.x, a, c), 0.f);
  v.y = fmaxf(fmaf(v.y, a, c), 0.f);
  v.z = fmaxf(fmaf(v.z, a, c), 0.f);
  v.w = fmaxf(fmaf(v.w, a, c), 0.f);
  ((float4*)out)[i] = v;
}

extern "C" void kernel_launch(void* const* d_in, const int* in_sizes, int n_in,
                              void* d_out, int out_size, void* d_ws, size_t ws_size,
                              hipStream_t stream) {
  const float* fea   = (const float*)d_in[0];
  const int*   ring  = (const int*)d_in[1];
  const float* W     = (const float*)d_in[2];
  const float* bias  = (const float*)d_in[3];
  const float* gamma = (const float*)d_in[4];
  const float* beta  = (const float*)d_in[5];
  float* out = (float*)d_out;

  u32* Gt = (u32*)d_ws;                                   // [B*4][Fn][8 u32] = 25.6 MB
  const size_t gtBytes = (size_t)Bn * 4 * Fn * 8 * 4;
  const size_t yBytes  = (size_t)Bn * 64 * (Fn / 2) * 4;  // 25.6 MB
  const bool bf16y = ws_size >= gtBytes + yBytes + 1024;

  u32* Y = (u32*)((char*)d_ws + gtBytes);
  float* gsum  = bf16y ? (float*)((char*)d_ws + gtBytes + yBytes)
                       : (float*)((char*)d_ws + gtBytes);
  float* gsum2 = gsum + 64;
  float* ab    = gsum + 128;

  // k1 zeroes gsum[0..127] -> no memset dispatch
  k1_mfma<<<dim3((Fn + 127) / 128, Bn), 256, 0, stream>>>(fea, W, Gt, gsum);
  const int ftiles = (Fn + 127) / 128;                    // 391
  if (bf16y) {
    k2_gather<1><<<dim3(ftiles * 16), 256, 0, stream>>>(Gt, ring, bias, Y, out, gsum, gsum2);
    k4_norm_bf<<<dim3(Bn * 64 * 12500 / 256), 256, 0, stream>>>(Y, gsum, gsum2, gamma, beta, out);
  } else {
    k2_gather<0><<<dim3(ftiles * 16), 256, 0, stream>>>(Gt, ring, bias, Y, out, gsum, gsum2);
    k3_stats<<<1, 64, 0, stream>>>(gsum, gsum2, gamma, beta, ab);
    k4_norm_f32<<<dim3((Bn * Cn * Fn / 4) / 256), 256, 0, stream>>>(out, ab);
  }
}